// Round 1
// baseline (5938.305 us; speedup 1.0000x reference)
//
#include <hip/hip_runtime.h>
#include <stdint.h>

#define Bdim 4
#define Tdim 2048
#define Vdim 32000
#define Hdim 512
#define MROWS (Bdim * Tdim)   // 8192

typedef unsigned short u16;
typedef __bf16 bf16x8 __attribute__((ext_vector_type(8)));
typedef float f32x4 __attribute__((ext_vector_type(4)));

__device__ __forceinline__ u16 f2bf(float f) {
  union { float f; uint32_t u; } a; a.f = f;
  uint32_t r = a.u + 0x7FFFu + ((a.u >> 16) & 1u);
  return (u16)(r >> 16);
}
__device__ __forceinline__ float bf2f(uint32_t lo16) {
  union { uint32_t u; float f; } a; a.u = lo16 << 16;
  return a.f;
}

// ---------------- embedding gather -> bf16 ----------------
__global__ void k_gather(const int* __restrict__ x, const float* __restrict__ embed,
                         u16* __restrict__ E) {
  int idx = blockIdx.x * 256 + threadIdx.x;   // one float4 per thread
  int row = idx >> 7;                          // 128 float4 per row
  int c4  = (idx & 127) << 2;
  int tok = x[row];
  const float4 v = *(const float4*)(embed + (size_t)tok * Hdim + c4);
  *(ushort4*)(E + (size_t)row * Hdim + c4) =
      make_ushort4(f2bf(v.x), f2bf(v.y), f2bf(v.z), f2bf(v.w));
}

// ---------------- fp32 -> bf16 convert ----------------
__global__ void k_f2b(const float* __restrict__ in, u16* __restrict__ out, int n4) {
  int idx = blockIdx.x * 256 + threadIdx.x;
  if (idx >= n4) return;
  const float4 v = *(const float4*)(in + (size_t)idx * 4);
  *(ushort4*)(out + (size_t)idx * 4) =
      make_ushort4(f2bf(v.x), f2bf(v.y), f2bf(v.z), f2bf(v.w));
}

// ---------------- bf16 MFMA GEMM: C = A @ Bw^T + bias1 (+bias2) ----------------
// A [M,K] bf16 row-major, Bw [N,K] bf16 row-major, C [M,N] fp32.
__device__ __forceinline__ void g2l16(const void* g, void* l) {
  __builtin_amdgcn_global_load_lds(
      (const __attribute__((address_space(1))) uint32_t*)g,
      (__attribute__((address_space(3))) uint32_t*)l, 16, 0, 0);
}

__global__ __launch_bounds__(256, 2) void k_gemm(
    const u16* __restrict__ A, const u16* __restrict__ Bw, float* __restrict__ C,
    const float* __restrict__ bias1, const float* __restrict__ bias2,
    int M, int N, int K, int ntN)
{
  __shared__ u16 Al[128 * 64];
  __shared__ u16 Bl[128 * 64];
  const int bid = blockIdx.x;
  const int mt = bid / ntN, nt = bid % ntN;
  const int m0 = mt << 7, n0 = nt << 7;
  const int tid = threadIdx.x;
  const int l = tid & 63, w = tid >> 6;
  const int wy = w >> 1, wx = w & 1;
  const int frow = l & 15, fk = (l >> 4) << 3;

  f32x4 acc[4][4];
  #pragma unroll
  for (int a = 0; a < 4; ++a)
    #pragma unroll
    for (int b = 0; b < 4; ++b) acc[a][b] = f32x4{0.f, 0.f, 0.f, 0.f};

  for (int kb = 0; kb < K; kb += 64) {
    __syncthreads();
    #pragma unroll
    for (int is = 0; is < 4; ++is) {
      const int off = tid * 16 + is * 4096;      // byte offset inside 16KB tile
      const int lrow = off >> 7, lcolB = off & 127;
      g2l16(A  + (size_t)(m0 + lrow) * K + kb + (lcolB >> 1), (char*)Al + off);
      g2l16(Bw + (size_t)(n0 + lrow) * K + kb + (lcolB >> 1), (char*)Bl + off);
    }
    __syncthreads();
    #pragma unroll
    for (int ks = 0; ks < 2; ++ks) {
      bf16x8 af[4], bfr[4];
      #pragma unroll
      for (int mi = 0; mi < 4; ++mi)
        af[mi] = *(const bf16x8*)&Al[((wy * 64 + mi * 16 + frow) << 6) + ks * 32 + fk];
      #pragma unroll
      for (int ni = 0; ni < 4; ++ni)
        bfr[ni] = *(const bf16x8*)&Bl[((wx * 64 + ni * 16 + frow) << 6) + ks * 32 + fk];
      #pragma unroll
      for (int mi = 0; mi < 4; ++mi)
        #pragma unroll
        for (int ni = 0; ni < 4; ++ni)
          acc[mi][ni] = __builtin_amdgcn_mfma_f32_16x16x32_bf16(af[mi], bfr[ni], acc[mi][ni], 0, 0, 0);
    }
  }
  #pragma unroll
  for (int ni = 0; ni < 4; ++ni) {
    const int col = n0 + wx * 64 + ni * 16 + (l & 15);
    float bv = bias1[col];
    if (bias2) bv += bias2[col];
    #pragma unroll
    for (int mi = 0; mi < 4; ++mi) {
      const int row = m0 + wy * 64 + mi * 16 + ((l >> 4) << 2);
      #pragma unroll
      for (int r = 0; r < 4; ++r)
        C[(size_t)(row + r) * N + col] = acc[mi][ni][r] + bv;
    }
  }
}

// ---------------- persistent RNN scan ----------------
// 64 WGs x 512 threads. WGs 0..31: layer0 (16 neurons each). WGs 32..63: layer1.
// h exchanged as bf16 pairs, value-as-flag (sentinel 0xFFFFFFFF = NaN|NaN).
#define SENT 0xFFFFFFFFu

__device__ __forceinline__ uint32_t aload(const uint32_t* p) {
  return __hip_atomic_load(p, __ATOMIC_RELAXED, __HIP_MEMORY_SCOPE_AGENT);
}
__device__ __forceinline__ void astore(uint32_t* p, uint32_t v) {
  __hip_atomic_store(p, v, __ATOMIC_RELAXED, __HIP_MEMORY_SCOPE_AGENT);
}

template <bool L1>
__device__ void scan_layer(const float* __restrict__ X0,
                           const float* __restrict__ WA,  // L0: Whh0 ; L1: Wih1
                           const float* __restrict__ WB,  // L1: Whh1
                           const float* __restrict__ bi1, const float* __restrict__ bi2,
                           uint32_t* __restrict__ H0b, uint32_t* __restrict__ H1b,
                           float* __restrict__ hfin, int slice)
{
  constexpr int KCH = L1 ? 32 : 16;   // float4 chunks per thread
  constexpr int SEG = KCH * 4;        // floats per thread (64 / 128)
  __shared__ float hs[Bdim * 1024];   // [b][0:512)=h_in, [b][512:1024)=h_self(prev) for L1
  const int tid = threadIdx.x;        // 512
  const int b  = tid >> 7;
  const int r  = tid & 127;
  const int i  = r >> 3;              // 0..15 neuron within slice
  const int kq = r & 7;               // 0..7 K-segment
  const int ig = slice * 16 + i;

  // weights in registers, pre-rotated by kq so LDS reads are conflict-free
  // with compile-time register indices.
  float wv[SEG];
  #pragma unroll
  for (int c = 0; c < KCH; ++c) {
    const int cc = (c + kq) & (KCH - 1);
    #pragma unroll
    for (int e = 0; e < 4; ++e) {
      const int k = kq * SEG + cc * 4 + e;
      if constexpr (L1) {
        wv[c * 4 + e] = (k < Hdim) ? WA[(size_t)ig * Hdim + k]
                                   : WB[(size_t)ig * Hdim + (k - Hdim)];
      } else {
        wv[c * 4 + e] = WA[(size_t)ig * Hdim + k];
      }
    }
  }
  float extra_c = 0.f;
  if constexpr (L1) extra_c = bi1[ig] + bi2[ig];

  #pragma unroll
  for (int j = 0; j < (Bdim * 1024) / 512; ++j) hs[tid + j * 512] = 0.f;
  __syncthreads();

  uint32_t* const Hout = L1 ? H1b : H0b;
  const int w0 = tid, w1 = tid + 512;  // word slots (1024 words = B*H/2)
  const int b0 = w0 >> 8, q0 = w0 & 255;
  const int b1 = w1 >> 8, q1 = w1 & 255;

  for (int t = 0; t < Tdim; ++t) {
    float extra = extra_c;
    if constexpr (!L1) extra = X0[(size_t)(b * Tdim + t) * Hdim + ig];  // early issue

    // ---- stage h into LDS ----
    if constexpr (L1) {
      const uint32_t* p0 = &H0b[(size_t)(b0 * Tdim + t) * 256 + q0];
      const uint32_t* p1 = &H0b[(size_t)(b1 * Tdim + t) * 256 + q1];
      uint32_t v0 = aload(p0), v1 = aload(p1), v2 = 0, v3 = 0;
      const uint32_t *p2 = p0, *p3 = p1;
      if (t > 0) {
        p2 = &H1b[(size_t)(b0 * Tdim + (t - 1)) * 256 + q0];
        p3 = &H1b[(size_t)(b1 * Tdim + (t - 1)) * 256 + q1];
        v2 = aload(p2); v3 = aload(p3);
      }
      while (v0 == SENT) v0 = aload(p0);
      while (v1 == SENT) v1 = aload(p1);
      if (t > 0) {
        while (v2 == SENT) v2 = aload(p2);
        while (v3 == SENT) v3 = aload(p3);
      }
      __syncthreads();  // prior compute done before overwriting hs
      *(float2*)&hs[b0 * 1024 + q0 * 2] = make_float2(bf2f(v0 & 0xFFFF), bf2f(v0 >> 16));
      *(float2*)&hs[b1 * 1024 + q1 * 2] = make_float2(bf2f(v1 & 0xFFFF), bf2f(v1 >> 16));
      if (t > 0) {
        *(float2*)&hs[b0 * 1024 + 512 + q0 * 2] = make_float2(bf2f(v2 & 0xFFFF), bf2f(v2 >> 16));
        *(float2*)&hs[b1 * 1024 + 512 + q1 * 2] = make_float2(bf2f(v3 & 0xFFFF), bf2f(v3 >> 16));
      }
      __syncthreads();
    } else {
      if (t > 0) {
        const uint32_t* p0 = &H0b[(size_t)(b0 * Tdim + (t - 1)) * 256 + q0];
        const uint32_t* p1 = &H0b[(size_t)(b1 * Tdim + (t - 1)) * 256 + q1];
        uint32_t v0 = aload(p0), v1 = aload(p1);
        while (v0 == SENT) v0 = aload(p0);
        while (v1 == SENT) v1 = aload(p1);
        __syncthreads();
        *(float2*)&hs[b0 * 1024 + q0 * 2] = make_float2(bf2f(v0 & 0xFFFF), bf2f(v0 >> 16));
        *(float2*)&hs[b1 * 1024 + q1 * 2] = make_float2(bf2f(v1 & 0xFFFF), bf2f(v1 >> 16));
        __syncthreads();
      }
    }

    // ---- matvec: sum over this thread's K segment ----
    float sum = 0.f;
    const float* hb = hs + b * 1024;
    #pragma unroll
    for (int c = 0; c < KCH; ++c) {
      const int cc = (c + kq) & (KCH - 1);
      const float4 hv = *(const float4*)&hb[kq * SEG + cc * 4];
      sum = fmaf(wv[c * 4 + 0], hv.x, sum);
      sum = fmaf(wv[c * 4 + 1], hv.y, sum);
      sum = fmaf(wv[c * 4 + 2], hv.z, sum);
      sum = fmaf(wv[c * 4 + 3], hv.w, sum);
    }
    sum += __shfl_xor(sum, 1);
    sum += __shfl_xor(sum, 2);
    sum += __shfl_xor(sum, 4);
    const float h  = tanhf(sum + extra);
    const float hp = __shfl_down(h, 8);   // neuron i+1's value (kq==0 lanes)
    if (kq == 0) {
      if ((i & 1) == 0) {
        const uint32_t wd = (uint32_t)f2bf(h) | ((uint32_t)f2bf(hp) << 16);
        astore(&Hout[(size_t)(b * Tdim + t) * 256 + (ig >> 1)], wd);
      }
      if (t == Tdim - 1)
        hfin[(L1 ? 1 : 0) * (Bdim * Hdim) + b * Hdim + ig] = h;
    }
  }
}

__global__ __launch_bounds__(512, 2) void k_scan(
    const float* __restrict__ X0, const float* __restrict__ W_ih,
    const float* __restrict__ W_hh, const float* __restrict__ b_ih,
    const float* __restrict__ b_hh, uint32_t* __restrict__ H0b,
    uint32_t* __restrict__ H1b, float* __restrict__ hfin)
{
  const int blk = blockIdx.x;
  if (blk < 32) {
    scan_layer<false>(X0, W_hh, nullptr, nullptr, nullptr, H0b, H1b, hfin, blk);
  } else {
    scan_layer<true>(nullptr, W_ih + Hdim * Hdim, W_hh + Hdim * Hdim,
                     b_ih + Hdim, b_hh + Hdim, H0b, H1b, hfin, blk - 32);
  }
}

// ---------------- launch ----------------
extern "C" void kernel_launch(void* const* d_in, const int* in_sizes, int n_in,
                              void* d_out, int out_size, void* d_ws, size_t ws_size,
                              hipStream_t stream)
{
  const int*   x     = (const int*)d_in[0];
  const float* embed = (const float*)d_in[1];
  const float* W_ih  = (const float*)d_in[2];
  const float* b_ih  = (const float*)d_in[3];
  const float* W_hh  = (const float*)d_in[4];
  const float* b_hh  = (const float*)d_in[5];
  const float* W_out = (const float*)d_in[6];
  const float* b_out = (const float*)d_in[7];
  float* out = (float*)d_out;

  // workspace layout (~75.3 MB)
  char* ws = (char*)d_ws;
  u16* E       = (u16*)ws;                                  // 8192*512 bf16
  u16* Wih0b   = E + (size_t)MROWS * Hdim;                  // 512*512
  u16* Woutb   = Wih0b + Hdim * Hdim;                       // 32000*512
  float* X0    = (float*)(Woutb + (size_t)Vdim * Hdim);     // 8192*512 f32
  uint32_t* H0b = (uint32_t*)(X0 + (size_t)MROWS * Hdim);   // 8192*256 words
  uint32_t* H1b = H0b + (size_t)MROWS * (Hdim / 2);

  k_gather<<<MROWS * (Hdim / 4) / 256, 256, 0, stream>>>(x, embed, E);
  k_f2b<<<(Hdim * Hdim / 4) / 256, 256, 0, stream>>>(W_ih, Wih0b, Hdim * Hdim / 4);
  k_f2b<<<(Vdim * Hdim / 4) / 256, 256, 0, stream>>>(W_out, Woutb, Vdim * Hdim / 4);

  // X0 = E @ Wih0^T + b_ih0 + b_hh0
  k_gemm<<<(MROWS / 128) * (Hdim / 128), 256, 0, stream>>>(
      E, Wih0b, X0, b_ih, b_hh, MROWS, Hdim, Hdim, Hdim / 128);

  hipMemsetAsync(H0b, 0xFF, (size_t)MROWS * (Hdim / 2) * 4, stream);
  hipMemsetAsync(H1b, 0xFF, (size_t)MROWS * (Hdim / 2) * 4, stream);

  float* hfin = out + (size_t)MROWS * Vdim;
  k_scan<<<64, 512, 0, stream>>>(X0, W_ih, W_hh, b_ih, b_hh, H0b, H1b, hfin);

  // out = H1 @ W_out^T + b_out
  k_gemm<<<(MROWS / 128) * (Vdim / 128), 256, 0, stream>>>(
      (const u16*)H1b, Woutb, out, b_out, nullptr, MROWS, Vdim, Hdim, Vdim / 128);
}